// Round 1
// baseline (312.895 us; speedup 1.0000x reference)
//
#include <hip/hip_runtime.h>
#include <stdint.h>

// DyDCNv2: modulated deformable 3x3 conv (stride1,pad1,no bias) + GroupNorm(16)
// B=8, C=256, O=256, H=W=64. fp32 in/out. Strategy: implicit GEMM
// M=32768,N=256,K=2304 in bf16 MFMA (fp32 accum), channels-last x repack for
// vectorized bilinear gather, fused GN stats.

#define B_ 8
#define C_ 256
#define O_ 256
#define H_ 64
#define W_ 64
#define HW_ 4096
#define KTOT 2304
#define GROUPS_ 16
#define EPS_ 1e-5f
#define NSTEPS 72          // K split: ck2 = k*256+c, 32 per step
#define WROW 40            // padded bf16 row (32 data + 8 pad) to break bank conflicts

// workspace layout (bytes)
#define XT_BYTES (B_*HW_*C_*4)                 // 33,554,432  x_t [B][HW][C] fp32
#define WIMG_OFF  XT_BYTES
#define WIMG_BYTES (NSTEPS*O_*WROW*2)          // 1,474,560   bf16 weight tile image
#define STATS_OFF (WIMG_OFF + WIMG_BYTES)      // 256 floats: sum[128], sumsq[128]
#define FIN_OFF   (STATS_OFF + 1024)           // 128 float2: {mean, inv_std}

typedef float  f32x4  __attribute__((ext_vector_type(4)));
typedef short  short8 __attribute__((ext_vector_type(8)));
typedef unsigned int   u32;
typedef unsigned short u16;

__device__ __forceinline__ u32 bf16r(float f) {  // RNE f32->bf16
    u32 u = __float_as_uint(f);
    return (u + 0x7fffu + ((u >> 16) & 1u)) >> 16;
}
__device__ __forceinline__ u32 pack_bf16x2(float lo, float hi) {
    return bf16r(lo) | (bf16r(hi) << 16);
}

// ---------------------------------------------------------------- transpose x
// x[B][C][HW] -> xt[B][HW][C], LDS-tiled 32x32
__global__ void k_transpose(const float* __restrict__ x, float* __restrict__ xt) {
    __shared__ float tile[32][33];
    const int b  = blockIdx.z;
    const int ct = blockIdx.y;   // c tile (8)
    const int pt = blockIdx.x;   // p tile (128)
    const int tx = threadIdx.x, ty = threadIdx.y;
    const int p = pt * 32 + tx;
#pragma unroll
    for (int i = 0; i < 4; ++i) {
        int c = ct * 32 + ty + i * 8;
        tile[ty + i * 8][tx] = x[(((size_t)b * C_ + c) << 12) + p];
    }
    __syncthreads();
    const int c2 = ct * 32 + tx;
#pragma unroll
    for (int i = 0; i < 4; ++i) {
        int p2 = pt * 32 + ty + i * 8;
        xt[((((size_t)b << 12) + p2) << 8) + c2] = tile[tx][ty + i * 8];
    }
}

// ---------------------------------------------------------------- pack weight
// weight[O][C][9] fp32 -> wimg[step][n][WROW] bf16, step = k*8 + ctile, j <-> c = ctile*32+j
__global__ void k_packw(const float* __restrict__ w, u16* __restrict__ wimg) {
    const int step = blockIdx.x;      // 72
    const int n = threadIdx.x;        // 256
    const int k  = step >> 3;
    const int c0 = (step & 7) * 32;
    const float* wr = w + (size_t)n * KTOT + k;   // + c*9
    u32 outw[20];
#pragma unroll
    for (int jj = 0; jj < 16; ++jj) {
        float f0 = wr[(size_t)(c0 + 2 * jj) * 9];
        float f1 = wr[(size_t)(c0 + 2 * jj + 1) * 9];
        outw[jj] = pack_bf16x2(f0, f1);
    }
#pragma unroll
    for (int jj = 16; jj < 20; ++jj) outw[jj] = 0u;
    u32* dst = (u32*)(wimg + ((size_t)step * O_ + n) * WROW);
#pragma unroll
    for (int jj = 0; jj < 20; ++jj) dst[jj] = outw[jj];
}

// ---------------------------------------------------------------- main fused DCN GEMM
// grid (2, 32, 8): n-tile(128) x m-tile(128 pos) x batch. 256 threads = 4 waves,
// wave tile 64x64 = 4x4 MFMA 16x16x32 bf16.
__launch_bounds__(256)
__global__ void k_dcn(const float* __restrict__ xt, const u16* __restrict__ wimg,
                      const float* __restrict__ offp, const float* __restrict__ mskp,
                      float* __restrict__ out, float* __restrict__ stats) {
    __shared__ __align__(16) u16 lds_w[128 * WROW];
    __shared__ __align__(16) u16 lds_v[128 * WROW];
    __shared__ __align__(16) float meta_w[128 * 4];
    __shared__ __align__(16) int   meta_i[128 * 4];

    const int tid  = threadIdx.x;
    const int n0   = blockIdx.x * 128;
    const int pos0 = blockIdx.y * 128;
    const int b    = blockIdx.z;

    const int lane = tid & 63;
    const int wid  = tid >> 6;
    const int col  = lane & 15;
    const int quad = lane >> 4;
    const int wm   = (wid & 1) * 64;
    const int wn   = (wid >> 1) * 64;

    const int oct  = tid & 3;        // gather: channel octet
    const int posL = tid >> 2;       // gather: position 0..63 (and +64)

    const float* xtb = xt + ((size_t)b << 20);   // b*HW*C

    f32x4 acc[4][4];
#pragma unroll
    for (int i = 0; i < 4; ++i)
#pragma unroll
        for (int j = 0; j < 4; ++j) acc[i][j] = (f32x4){0.f, 0.f, 0.f, 0.f};

    for (int step = 0; step < NSTEPS; ++step) {
        const int k  = step >> 3;
        const int c0 = (step & 7) * 32;

        __syncthreads();   // previous step's MFMA reads done

        if ((step & 7) == 0) {   // new k: rebuild bilinear meta for 128 positions
            if (tid < 128) {
                const int pos = tid;
                const int pg  = pos0 + pos;
                const int hh  = pg >> 6, wwi = pg & 63;
                const float dy = offp[((size_t)(b * 18 + 2 * k) << 12) + pg];
                const float dx = offp[((size_t)(b * 18 + 2 * k + 1) << 12) + pg];
                const float mv = mskp[((size_t)(b * 9 + k) << 12) + pg];
                const float ys = (float)(hh + (k / 3) - 1) + dy;
                const float xs = (float)(wwi + (k % 3) - 1) + dx;
                const float y0f = floorf(ys), x0f = floorf(xs);
                const int y0 = (int)y0f, x0 = (int)x0f;
                const float wy1 = ys - y0f, wx1 = xs - x0f;
                const float wy0 = 1.f - wy1, wx0 = 1.f - wx1;
                const int y1 = y0 + 1, x1 = x0 + 1;
                const float vy0 = (y0 >= 0 && y0 < H_) ? 1.f : 0.f;
                const float vy1 = (y1 >= 0 && y1 < H_) ? 1.f : 0.f;
                const float vx0 = (x0 >= 0 && x0 < W_) ? 1.f : 0.f;
                const float vx1 = (x1 >= 0 && x1 < W_) ? 1.f : 0.f;
                const int y0c = min(max(y0, 0), H_ - 1), y1c = min(max(y1, 0), H_ - 1);
                const int x0c = min(max(x0, 0), W_ - 1), x1c = min(max(x1, 0), W_ - 1);
                meta_w[pos * 4 + 0] = mv * wy0 * wx0 * vy0 * vx0;
                meta_w[pos * 4 + 1] = mv * wy0 * wx1 * vy0 * vx1;
                meta_w[pos * 4 + 2] = mv * wy1 * wx0 * vy1 * vx0;
                meta_w[pos * 4 + 3] = mv * wy1 * wx1 * vy1 * vx1;
                meta_i[pos * 4 + 0] = y0c * W_ + x0c;
                meta_i[pos * 4 + 1] = y0c * W_ + x1c;
                meta_i[pos * 4 + 2] = y1c * W_ + x0c;
                meta_i[pos * 4 + 3] = y1c * W_ + x1c;
            }
            __syncthreads();
        }

        // stage weight tile (rows n0..n0+127), 10240 B = 640 uint4
        {
            const uint4* src = (const uint4*)(wimg + ((size_t)step * O_ + n0) * WROW);
            uint4* dst = (uint4*)lds_w;
            for (int i = tid; i < 640; i += 256) dst[i] = src[i];
        }

        // gather val tile: 128 pos x 32 ch (c0..c0+31), bf16 into lds_v
        {
            const float* cbase = xtb + c0 + (oct << 3);
#pragma unroll
            for (int pp = 0; pp < 2; ++pp) {
                const int pos = posL + pp * 64;
                const float w0 = meta_w[pos * 4 + 0], w1 = meta_w[pos * 4 + 1];
                const float w2 = meta_w[pos * 4 + 2], w3 = meta_w[pos * 4 + 3];
                const int i0 = meta_i[pos * 4 + 0], i1 = meta_i[pos * 4 + 1];
                const int i2 = meta_i[pos * 4 + 2], i3 = meta_i[pos * 4 + 3];
                const f32x4* p0 = (const f32x4*)(cbase + ((size_t)i0 << 8));
                const f32x4* p1 = (const f32x4*)(cbase + ((size_t)i1 << 8));
                const f32x4* p2 = (const f32x4*)(cbase + ((size_t)i2 << 8));
                const f32x4* p3 = (const f32x4*)(cbase + ((size_t)i3 << 8));
                f32x4 s0 = p0[0] * w0 + p1[0] * w1 + p2[0] * w2 + p3[0] * w3;
                f32x4 s1 = p0[1] * w0 + p1[1] * w1 + p2[1] * w2 + p3[1] * w3;
                uint4 pk;
                pk.x = pack_bf16x2(s0.x, s0.y);
                pk.y = pack_bf16x2(s0.z, s0.w);
                pk.z = pack_bf16x2(s1.x, s1.y);
                pk.w = pack_bf16x2(s1.z, s1.w);
                *(uint4*)(&lds_v[pos * WROW + (oct << 3)]) = pk;
            }
        }

        __syncthreads();   // tiles ready

        short8 af[4], bfr[4];
#pragma unroll
        for (int mi = 0; mi < 4; ++mi)
            af[mi] = *(const short8*)&lds_v[(wm + mi * 16 + col) * WROW + quad * 8];
#pragma unroll
        for (int ni = 0; ni < 4; ++ni)
            bfr[ni] = *(const short8*)&lds_w[(wn + ni * 16 + col) * WROW + quad * 8];
#pragma unroll
        for (int mi = 0; mi < 4; ++mi)
#pragma unroll
            for (int ni = 0; ni < 4; ++ni)
                acc[mi][ni] = __builtin_amdgcn_mfma_f32_16x16x32_bf16(
                    af[mi], bfr[ni], acc[mi][ni], 0, 0, 0);
    }

    // epilogue: store DCN output (pre-GN). D layout: row(pos)=quad*4+r, col(o)=lane&15.
#pragma unroll
    for (int mi = 0; mi < 4; ++mi)
#pragma unroll
        for (int ni = 0; ni < 4; ++ni) {
            const int o  = n0 + wn + ni * 16 + col;
            const int pg = pos0 + wm + mi * 16 + quad * 4;
            *(f32x4*)(out + (((size_t)b * O_ + o) << 12) + pg) = acc[mi][ni];
        }

    // GN stats: each (wave, ni) covers exactly one 16-channel group x 64 positions
#pragma unroll
    for (int ni = 0; ni < 4; ++ni) {
        float s = 0.f, s2 = 0.f;
#pragma unroll
        for (int mi = 0; mi < 4; ++mi) {
            f32x4 v = acc[mi][ni];
            s  += v.x + v.y + v.z + v.w;
            s2 += v.x * v.x + v.y * v.y + v.z * v.z + v.w * v.w;
        }
#pragma unroll
        for (int d = 32; d > 0; d >>= 1) {
            s  += __shfl_xor(s, d, 64);
            s2 += __shfl_xor(s2, d, 64);
        }
        if (lane == 0) {
            const int g = (n0 + wn + ni * 16) >> 4;
            atomicAdd(&stats[b * GROUPS_ + g], s);
            atomicAdd(&stats[128 + b * GROUPS_ + g], s2);
        }
    }
}

// ---------------------------------------------------------------- stats finalize
__global__ void k_fin(const float* __restrict__ stats, float2* __restrict__ fin) {
    const int t = threadIdx.x;
    if (t < 128) {
        const float n = 65536.f;   // (C/G)*H*W
        float mean = stats[t] / n;
        float var  = stats[128 + t] / n - mean * mean;
        fin[t] = make_float2(mean, rsqrtf(fmaxf(var, 0.f) + EPS_));
    }
}

// ---------------------------------------------------------------- apply GN in place
__global__ void k_gn(float* __restrict__ out, const float2* __restrict__ fin,
                     const float* __restrict__ gamma, const float* __restrict__ beta) {
    const int blk = blockIdx.x;            // b*256 + o
    const int b = blk >> 8, o = blk & 255;
    const float2 mi = fin[b * GROUPS_ + (o >> 4)];
    const float scale = mi.y * gamma[o];
    const float shift = beta[o] - mi.x * scale;
    f32x4* p = (f32x4*)(out + ((size_t)blk << 12));
    const int t = threadIdx.x;
#pragma unroll
    for (int i = 0; i < 4; ++i) {
        f32x4 v = p[t + i * 256];
        p[t + i * 256] = v * scale + shift;
    }
}

extern "C" void kernel_launch(void* const* d_in, const int* in_sizes, int n_in,
                              void* d_out, int out_size, void* d_ws, size_t ws_size,
                              hipStream_t stream) {
    const float* x     = (const float*)d_in[0];
    const float* offp  = (const float*)d_in[1];
    const float* mskp  = (const float*)d_in[2];
    const float* w     = (const float*)d_in[3];
    const float* gamma = (const float*)d_in[4];
    const float* beta  = (const float*)d_in[5];
    float* outp = (float*)d_out;

    float* xt    = (float*)d_ws;
    u16*   wimg  = (u16*)((char*)d_ws + WIMG_OFF);
    float* stats = (float*)((char*)d_ws + STATS_OFF);
    float2* fin  = (float2*)((char*)d_ws + FIN_OFF);

    hipMemsetAsync(stats, 0, 1024, stream);
    k_transpose<<<dim3(128, 8, 8), dim3(32, 8, 1), 0, stream>>>(x, xt);
    k_packw<<<dim3(NSTEPS), dim3(256), 0, stream>>>(w, wimg);
    k_dcn<<<dim3(2, 32, 8), dim3(256), 0, stream>>>(xt, wimg, offp, mskp, outp, stats);
    k_fin<<<dim3(1), dim3(128), 0, stream>>>(stats, fin);
    k_gn<<<dim3(2048), dim3(256), 0, stream>>>(outp, fin, gamma, beta);
}

// Round 2
// 233.966 us; speedup vs baseline: 1.3374x; 1.3374x over previous
//
#include <hip/hip_runtime.h>
#include <stdint.h>

// DyDCNv2 + GroupNorm(16). B=8, C=O=256, H=W=64, fp32 in/out.
// Implicit GEMM M=32768,N=256,K=2304 bf16 MFMA. Round 2: bf16 channels-last x
// (1 line per corner gather), frag-packed weights global->reg (no lds_w),
// meta precompute + single-barrier double-buffered pipeline, 64x256 tiles.

#define B_ 8
#define C_ 256
#define O_ 256
#define H_ 64
#define W_ 64
#define HW_ 4096
#define KTOT 2304
#define GROUPS_ 16
#define EPS_ 1e-5f
#define NSTEPS 72          // K = 9 kpts * 8 ctiles of 32

typedef float  f32x4  __attribute__((ext_vector_type(4)));
typedef short  short8 __attribute__((ext_vector_type(8)));
typedef unsigned int   u32;
typedef unsigned short u16;

// workspace layout (bytes)
#define XT_BYTES (B_*HW_*C_*2)                 // 16,777,216  xt [B][HW][C] bf16
#define WIMG_OFF  XT_BYTES
#define WIMG_BYTES (NSTEPS*16*64*16)           // 1,179,648  frag-packed bf16 weights
#define STATS_OFF (WIMG_OFF + WIMG_BYTES)      // 256 floats
#define FIN_OFF   (STATS_OFF + 1024)

__device__ __forceinline__ u32 bf16r(float f) {  // RNE f32->bf16
    u32 u = __float_as_uint(f);
    return (u + 0x7fffu + ((u >> 16) & 1u)) >> 16;
}
__device__ __forceinline__ u32 pack_bf16x2(float lo, float hi) {
    return bf16r(lo) | (bf16r(hi) << 16);
}
__device__ __forceinline__ float bflo(u32 u) { return __uint_as_float(u << 16); }
__device__ __forceinline__ float bfhi(u32 u) { return __uint_as_float(u & 0xffff0000u); }

// ---------------------------------------------------------------- transpose x -> bf16 channels-last
__global__ void k_transpose(const float* __restrict__ x, u16* __restrict__ xt) {
    __shared__ float tile[32][33];
    const int b  = blockIdx.z;
    const int ct = blockIdx.y;   // c tile (8)
    const int pt = blockIdx.x;   // p tile (128)
    const int tx = threadIdx.x, ty = threadIdx.y;
    const int p = pt * 32 + tx;
#pragma unroll
    for (int i = 0; i < 4; ++i) {
        int c = ct * 32 + ty + i * 8;
        tile[ty + i * 8][tx] = x[(((size_t)b * C_ + c) << 12) + p];
    }
    __syncthreads();
    const int cp = tx & 15;                // channel pair 0..15
    const int ps = ty + (tx >> 4) * 8;     // p sub-row 0..15
#pragma unroll
    for (int i = 0; i < 2; ++i) {
        const int pl = ps + i * 16;
        u32 v = pack_bf16x2(tile[2 * cp][pl], tile[2 * cp + 1][pl]);
        *(u32*)&xt[((((size_t)b << 12) + pt * 32 + pl) << 8) + ct * 32 + 2 * cp] = v;
    }
}

// ---------------------------------------------------------------- pack weights in B-frag layout
// wimg[step][frag 0..15][lane 0..63][8 bf16]: lane(col,quad) holds
// W[n=frag*16+col][c=c0+quad*8+j][k], step=k*8+ctile.
__global__ void k_packw(const float* __restrict__ w, u16* __restrict__ wimg) {
    const int step = blockIdx.x;      // 72
    const int t = threadIdx.x;        // 256
    const int k  = step >> 3;
    const int c0 = (step & 7) * 32;
#pragma unroll
    for (int i = 0; i < 4; ++i) {
        const int item = t + i * 256;          // 0..1023 = frag*64 + lane
        const int lane = item & 63;
        const int frag = item >> 6;
        const int col = lane & 15, quad = lane >> 4;
        const int n = frag * 16 + col;
        const float* src = w + (size_t)n * KTOT + (size_t)(c0 + quad * 8) * 9 + k;
        u32 o[4];
#pragma unroll
        for (int j = 0; j < 4; ++j)
            o[j] = pack_bf16x2(src[(size_t)(2 * j) * 9], src[(size_t)(2 * j + 1) * 9]);
        *(uint4*)&wimg[((size_t)step * 1024 + item) * 8] = *(uint4*)o;
    }
}

// ---------------------------------------------------------------- main fused DCN GEMM
// grid (64, 8): 64-pos tile x batch. 256 threads = 4 waves; wave w: 64 pos x n[w*64, w*64+64).
__launch_bounds__(256)
__global__ void k_dcn(const u16* __restrict__ xt, const u16* __restrict__ wimg,
                      const float* __restrict__ offp, const float* __restrict__ mskp,
                      float* __restrict__ out, float* __restrict__ stats) {
    __shared__ __align__(16) float meta_w[9 * 64 * 4];   // 9216 B
    __shared__ __align__(16) int   meta_i[9 * 64 * 4];   // 9216 B
    __shared__ __align__(16) u16   lds_v[2][64 * 32];    // 8192 B dbuf val tile

    const int tid = threadIdx.x;
    const int m0  = blockIdx.x * 64;
    const int b   = blockIdx.y;
    const int lane = tid & 63, wid = tid >> 6;
    const int col = lane & 15, quad = lane >> 4;
    const int gpos = tid >> 2, oct = tid & 3;   // gather role: (pos, channel-octet)

    const u16* xtb = xt + ((size_t)b << 20);    // b*HW*C (u16 units)

    // ---- bilinear meta for 64 positions x 9 kernel points, once
    for (int it = tid; it < 576; it += 256) {
        const int pos = it & 63, k = it >> 6;
        const int pg = m0 + pos;
        const int hh = pg >> 6, wwi = pg & 63;
        const float dy = offp[((size_t)(b * 18 + 2 * k) << 12) + pg];
        const float dx = offp[((size_t)(b * 18 + 2 * k + 1) << 12) + pg];
        const float mv = mskp[((size_t)(b * 9 + k) << 12) + pg];
        const float ys = (float)(hh + (k / 3) - 1) + dy;
        const float xs = (float)(wwi + (k % 3) - 1) + dx;
        const float y0f = floorf(ys), x0f = floorf(xs);
        const int y0 = (int)y0f, x0 = (int)x0f;
        const float wy1 = ys - y0f, wx1 = xs - x0f;
        const float wy0 = 1.f - wy1, wx0 = 1.f - wx1;
        const int y1 = y0 + 1, x1 = x0 + 1;
        const float vy0 = (y0 >= 0 && y0 < H_) ? 1.f : 0.f;
        const float vy1 = (y1 >= 0 && y1 < H_) ? 1.f : 0.f;
        const float vx0 = (x0 >= 0 && x0 < W_) ? 1.f : 0.f;
        const float vx1 = (x1 >= 0 && x1 < W_) ? 1.f : 0.f;
        const int y0c = min(max(y0, 0), H_ - 1), y1c = min(max(y1, 0), H_ - 1);
        const int x0c = min(max(x0, 0), W_ - 1), x1c = min(max(x1, 0), W_ - 1);
        meta_w[it * 4 + 0] = mv * wy0 * wx0 * vy0 * vx0;
        meta_w[it * 4 + 1] = mv * wy0 * wx1 * vy0 * vx1;
        meta_w[it * 4 + 2] = mv * wy1 * wx0 * vy1 * vx0;
        meta_w[it * 4 + 3] = mv * wy1 * wx1 * vy1 * vx1;
        meta_i[it * 4 + 0] = y0c * W_ + x0c;
        meta_i[it * 4 + 1] = y0c * W_ + x1c;
        meta_i[it * 4 + 2] = y1c * W_ + x0c;
        meta_i[it * 4 + 3] = y1c * W_ + x1c;
    }
    __syncthreads();

    // ---- prologue: gather step 0 into buf 0; prefetch weight frags step 0
    {
        const f32x4 mw = *(const f32x4*)&meta_w[gpos * 4];    // k=0
        const int4  ix = *(const int4*)&meta_i[gpos * 4];
        const u16* cb = xtb + oct * 8;                        // c0=0
        const uint4 g0 = *(const uint4*)(cb + ((size_t)ix.x << 8));
        const uint4 g1 = *(const uint4*)(cb + ((size_t)ix.y << 8));
        const uint4 g2 = *(const uint4*)(cb + ((size_t)ix.z << 8));
        const uint4 g3 = *(const uint4*)(cb + ((size_t)ix.w << 8));
        float s[8] = {0, 0, 0, 0, 0, 0, 0, 0};
        const uint4 gg[4] = {g0, g1, g2, g3};
        const float ww[4] = {mw.x, mw.y, mw.z, mw.w};
#pragma unroll
        for (int cr = 0; cr < 4; ++cr) {
            const float wg = ww[cr];
            s[0] += wg * bflo(gg[cr].x); s[1] += wg * bfhi(gg[cr].x);
            s[2] += wg * bflo(gg[cr].y); s[3] += wg * bfhi(gg[cr].y);
            s[4] += wg * bflo(gg[cr].z); s[5] += wg * bfhi(gg[cr].z);
            s[6] += wg * bflo(gg[cr].w); s[7] += wg * bfhi(gg[cr].w);
        }
        uint4 pk;
        pk.x = pack_bf16x2(s[0], s[1]); pk.y = pack_bf16x2(s[2], s[3]);
        pk.z = pack_bf16x2(s[4], s[5]); pk.w = pack_bf16x2(s[6], s[7]);
        *(uint4*)&lds_v[0][gpos * 32 + oct * 8] = pk;
    }
    short8 bfp[4];
#pragma unroll
    for (int ni = 0; ni < 4; ++ni)
        bfp[ni] = *(const short8*)&wimg[(((size_t)0 * 16 + wid * 4 + ni) * 64 + lane) * 8];
    __syncthreads();

    f32x4 acc[4][4];
#pragma unroll
    for (int i = 0; i < 4; ++i)
#pragma unroll
        for (int j = 0; j < 4; ++j) acc[i][j] = (f32x4){0.f, 0.f, 0.f, 0.f};

#pragma unroll 2
    for (int step = 0; step < NSTEPS; ++step) {
        const int p = step & 1;

        // A-frags for current step
        short8 af[4];
#pragma unroll
        for (int mi = 0; mi < 4; ++mi)
            af[mi] = *(const short8*)&lds_v[p][(mi * 16 + col) * 32 + quad * 8];
        short8 bfc[4];
#pragma unroll
        for (int ni = 0; ni < 4; ++ni) bfc[ni] = bfp[ni];

        // issue next step's loads (gather + weight frags) before MFMA
        const bool pf = (step + 1 < NSTEPS);
        uint4 g0, g1, g2, g3;
        f32x4 mw;
        if (pf) {
            const int sn = step + 1;
            const int kn = sn >> 3, c0n = (sn & 7) * 32;
            mw = *(const f32x4*)&meta_w[(kn * 64 + gpos) * 4];
            const int4 ix = *(const int4*)&meta_i[(kn * 64 + gpos) * 4];
            const u16* cb = xtb + c0n + oct * 8;
            g0 = *(const uint4*)(cb + ((size_t)ix.x << 8));
            g1 = *(const uint4*)(cb + ((size_t)ix.y << 8));
            g2 = *(const uint4*)(cb + ((size_t)ix.z << 8));
            g3 = *(const uint4*)(cb + ((size_t)ix.w << 8));
#pragma unroll
            for (int ni = 0; ni < 4; ++ni)
                bfp[ni] = *(const short8*)&wimg[(((size_t)sn * 16 + wid * 4 + ni) * 64 + lane) * 8];
        }

        // MFMA on current step
#pragma unroll
        for (int mi = 0; mi < 4; ++mi)
#pragma unroll
            for (int ni = 0; ni < 4; ++ni)
                acc[mi][ni] = __builtin_amdgcn_mfma_f32_16x16x32_bf16(
                    af[mi], bfc[ni], acc[mi][ni], 0, 0, 0);

        // interpolate + pack + stage next step's val tile
        if (pf) {
            float s[8] = {0, 0, 0, 0, 0, 0, 0, 0};
            const uint4 gg[4] = {g0, g1, g2, g3};
            const float ww[4] = {mw.x, mw.y, mw.z, mw.w};
#pragma unroll
            for (int cr = 0; cr < 4; ++cr) {
                const float wg = ww[cr];
                s[0] += wg * bflo(gg[cr].x); s[1] += wg * bfhi(gg[cr].x);
                s[2] += wg * bflo(gg[cr].y); s[3] += wg * bfhi(gg[cr].y);
                s[4] += wg * bflo(gg[cr].z); s[5] += wg * bfhi(gg[cr].z);
                s[6] += wg * bflo(gg[cr].w); s[7] += wg * bfhi(gg[cr].w);
            }
            uint4 pk;
            pk.x = pack_bf16x2(s[0], s[1]); pk.y = pack_bf16x2(s[2], s[3]);
            pk.z = pack_bf16x2(s[4], s[5]); pk.w = pack_bf16x2(s[6], s[7]);
            *(uint4*)&lds_v[1 - p][gpos * 32 + oct * 8] = pk;
        }
        __syncthreads();
    }

    // ---- epilogue: store pre-GN output. D: row(pos)=quad*4+r, col(o)=lane&15.
#pragma unroll
    for (int mi = 0; mi < 4; ++mi)
#pragma unroll
        for (int ni = 0; ni < 4; ++ni) {
            const int o  = wid * 64 + ni * 16 + col;
            const int pg = m0 + mi * 16 + quad * 4;
            *(f32x4*)(out + (((size_t)b * O_ + o) << 12) + pg) = acc[mi][ni];
        }

    // ---- GN stats: (wave, ni) = one 16-channel group x 64 positions
#pragma unroll
    for (int ni = 0; ni < 4; ++ni) {
        float s = 0.f, s2 = 0.f;
#pragma unroll
        for (int mi = 0; mi < 4; ++mi) {
            f32x4 v = acc[mi][ni];
            s  += v.x + v.y + v.z + v.w;
            s2 += v.x * v.x + v.y * v.y + v.z * v.z + v.w * v.w;
        }
#pragma unroll
        for (int d = 32; d > 0; d >>= 1) {
            s  += __shfl_xor(s, d, 64);
            s2 += __shfl_xor(s2, d, 64);
        }
        if (lane == 0) {
            const int g = wid * 4 + ni;
            atomicAdd(&stats[b * GROUPS_ + g], s);
            atomicAdd(&stats[128 + b * GROUPS_ + g], s2);
        }
    }
}

// ---------------------------------------------------------------- stats finalize
__global__ void k_fin(const float* __restrict__ stats, float2* __restrict__ fin) {
    const int t = threadIdx.x;
    if (t < 128) {
        const float n = 65536.f;   // (C/G)*H*W
        float mean = stats[t] / n;
        float var  = stats[128 + t] / n - mean * mean;
        fin[t] = make_float2(mean, rsqrtf(fmaxf(var, 0.f) + EPS_));
    }
}

// ---------------------------------------------------------------- apply GN in place
__global__ void k_gn(float* __restrict__ out, const float2* __restrict__ fin,
                     const float* __restrict__ gamma, const float* __restrict__ beta) {
    const int blk = blockIdx.x;            // b*256 + o
    const int b = blk >> 8, o = blk & 255;
    const float2 mi = fin[b * GROUPS_ + (o >> 4)];
    const float scale = mi.y * gamma[o];
    const float shift = beta[o] - mi.x * scale;
    f32x4* p = (f32x4*)(out + ((size_t)blk << 12));
    const int t = threadIdx.x;
#pragma unroll
    for (int i = 0; i < 4; ++i) {
        f32x4 v = p[t + i * 256];
        p[t + i * 256] = v * scale + shift;
    }
}

extern "C" void kernel_launch(void* const* d_in, const int* in_sizes, int n_in,
                              void* d_out, int out_size, void* d_ws, size_t ws_size,
                              hipStream_t stream) {
    const float* x     = (const float*)d_in[0];
    const float* offp  = (const float*)d_in[1];
    const float* mskp  = (const float*)d_in[2];
    const float* w     = (const float*)d_in[3];
    const float* gamma = (const float*)d_in[4];
    const float* beta  = (const float*)d_in[5];
    float* outp = (float*)d_out;

    u16*   xt    = (u16*)d_ws;
    u16*   wimg  = (u16*)((char*)d_ws + WIMG_OFF);
    float* stats = (float*)((char*)d_ws + STATS_OFF);
    float2* fin  = (float2*)((char*)d_ws + FIN_OFF);

    hipMemsetAsync(stats, 0, 1024, stream);
    k_transpose<<<dim3(128, 8, 8), dim3(32, 8, 1), 0, stream>>>(x, xt);
    k_packw<<<dim3(NSTEPS), dim3(256), 0, stream>>>(w, wimg);
    k_dcn<<<dim3(64, 8), dim3(256), 0, stream>>>(xt, wimg, offp, mskp, outp, stats);
    k_fin<<<dim3(1), dim3(128), 0, stream>>>(stats, fin);
    k_gn<<<dim3(2048), dim3(256), 0, stream>>>(outp, fin, gamma, beta);
}

// Round 3
// 201.349 us; speedup vs baseline: 1.5540x; 1.1620x over previous
//
#include <hip/hip_runtime.h>
#include <stdint.h>

// DyDCNv2 + GroupNorm(16). B=8, C=O=256, H=W=64, fp32 in/out.
// Implicit GEMM M=32768,N=256,K=2304 bf16 MFMA.
// R3: XCD-affine batch swizzle (per-XCD L2-resident xt), 64-ch K-steps
// (36 barriers), padded LDS val rows (144B, conflict-free), fused prep/GN.

#define B_ 8
#define C_ 256
#define O_ 256
#define H_ 64
#define W_ 64
#define HW_ 4096
#define KTOT 2304
#define GROUPS_ 16
#define EPS_ 1e-5f
#define NSTEP 36           // 36 steps x 64 ch
#define VROW 72            // lds_v row stride in u16 (64 data + 8 pad)

typedef float  f32x4  __attribute__((ext_vector_type(4)));
typedef short  short8 __attribute__((ext_vector_type(8)));
typedef unsigned int   u32;
typedef unsigned short u16;

// workspace layout (bytes)
#define XT_BYTES (B_*HW_*C_*2)                 // 16,777,216  xt [B][HW][C] bf16
#define WIMG_OFF  XT_BYTES
#define WIMG_BYTES (72*16*64*16)               // 1,179,648  frag-packed bf16 weights
#define STATS_OFF (WIMG_OFF + WIMG_BYTES)      // 256 floats

__device__ __forceinline__ u32 bf16r(float f) {  // RNE f32->bf16
    u32 u = __float_as_uint(f);
    return (u + 0x7fffu + ((u >> 16) & 1u)) >> 16;
}
__device__ __forceinline__ u32 pack_bf16x2(float lo, float hi) {
    return bf16r(lo) | (bf16r(hi) << 16);
}
__device__ __forceinline__ float bflo(u32 u) { return __uint_as_float(u << 16); }
__device__ __forceinline__ float bfhi(u32 u) { return __uint_as_float(u & 0xffff0000u); }

// ---------------------------------------------------------------- prep: transpose + packw fused
__global__ void k_prep(const float* __restrict__ x, u16* __restrict__ xt,
                       const float* __restrict__ w, u16* __restrict__ wimg) {
    __shared__ float tile[32][33];
    const int bid = blockIdx.x;
    const int tid = threadIdx.x;
    if (bid < 8192) {
        // transpose x[B][C][HW] -> xt[B][HW][C] bf16
        const int pt = bid & 127, ct = (bid >> 7) & 7, b = bid >> 10;
        const int tx = tid & 31, ty = tid >> 5;
        const int p = pt * 32 + tx;
#pragma unroll
        for (int i = 0; i < 4; ++i) {
            int c = ct * 32 + ty + i * 8;
            tile[ty + i * 8][tx] = x[(((size_t)b * C_ + c) << 12) + p];
        }
        __syncthreads();
        const int cp = tx & 15;
        const int ps = ty + (tx >> 4) * 8;
#pragma unroll
        for (int i = 0; i < 2; ++i) {
            const int pl = ps + i * 16;
            u32 v = pack_bf16x2(tile[2 * cp][pl], tile[2 * cp + 1][pl]);
            *(u32*)&xt[((((size_t)b << 12) + pt * 32 + pl) << 8) + ct * 32 + 2 * cp] = v;
        }
    } else {
        // pack weights: wimg[sub][frag][lane][8], sub = k*8+ctile;
        // lane(col,quad) holds W[n=frag*16+col][c0+quad*8+j][k]
        const int sub = bid - 8192;       // 0..71
        const int k  = sub >> 3;
        const int c0 = (sub & 7) * 32;
#pragma unroll
        for (int i = 0; i < 4; ++i) {
            const int item = tid + i * 256;    // frag*64 + lane
            const int lane = item & 63;
            const int frag = item >> 6;
            const int col = lane & 15, quad = lane >> 4;
            const int n = frag * 16 + col;
            const float* src = w + (size_t)n * KTOT + (size_t)(c0 + quad * 8) * 9 + k;
            u32 o[4];
#pragma unroll
            for (int j = 0; j < 4; ++j)
                o[j] = pack_bf16x2(src[(size_t)(2 * j) * 9], src[(size_t)(2 * j + 1) * 9]);
            *(uint4*)&wimg[((size_t)sub * 1024 + item) * 8] = *(uint4*)o;
        }
    }
}

// ---------------------------------------------------------------- k_dcn helpers
__device__ __forceinline__ void issue_gather(const u16* __restrict__ xtb,
                                             const float* __restrict__ mwp,
                                             const int* __restrict__ mip,
                                             int c0, int gpos, int oct,
                                             uint4 g[8], f32x4& mw) {
    mw = *(const f32x4*)&mwp[gpos * 4];
    const int4 ix = *(const int4*)&mip[gpos * 4];
    const u16* cb = xtb + c0 + oct * 16;
    const u16* p0 = cb + ((size_t)ix.x << 8);
    const u16* p1 = cb + ((size_t)ix.y << 8);
    const u16* p2 = cb + ((size_t)ix.z << 8);
    const u16* p3 = cb + ((size_t)ix.w << 8);
    g[0] = *(const uint4*)p0; g[1] = *(const uint4*)(p0 + 8);
    g[2] = *(const uint4*)p1; g[3] = *(const uint4*)(p1 + 8);
    g[4] = *(const uint4*)p2; g[5] = *(const uint4*)(p2 + 8);
    g[6] = *(const uint4*)p3; g[7] = *(const uint4*)(p3 + 8);
}

__device__ __forceinline__ void interp_store(const uint4 g[8], f32x4 mw, u16* dst) {
    float s[16];
#pragma unroll
    for (int i = 0; i < 16; ++i) s[i] = 0.f;
    const float ww[4] = {mw.x, mw.y, mw.z, mw.w};
#pragma unroll
    for (int cr = 0; cr < 4; ++cr) {
        const float wg = ww[cr];
        const uint4 a = g[2 * cr], bq = g[2 * cr + 1];
        s[0] += wg * bflo(a.x);  s[1] += wg * bfhi(a.x);
        s[2] += wg * bflo(a.y);  s[3] += wg * bfhi(a.y);
        s[4] += wg * bflo(a.z);  s[5] += wg * bfhi(a.z);
        s[6] += wg * bflo(a.w);  s[7] += wg * bfhi(a.w);
        s[8]  += wg * bflo(bq.x); s[9]  += wg * bfhi(bq.x);
        s[10] += wg * bflo(bq.y); s[11] += wg * bfhi(bq.y);
        s[12] += wg * bflo(bq.z); s[13] += wg * bfhi(bq.z);
        s[14] += wg * bflo(bq.w); s[15] += wg * bfhi(bq.w);
    }
    uint4 pk0, pk1;
    pk0.x = pack_bf16x2(s[0], s[1]);   pk0.y = pack_bf16x2(s[2], s[3]);
    pk0.z = pack_bf16x2(s[4], s[5]);   pk0.w = pack_bf16x2(s[6], s[7]);
    pk1.x = pack_bf16x2(s[8], s[9]);   pk1.y = pack_bf16x2(s[10], s[11]);
    pk1.z = pack_bf16x2(s[12], s[13]); pk1.w = pack_bf16x2(s[14], s[15]);
    *(uint4*)dst = pk0;
    *(uint4*)(dst + 8) = pk1;
}

__device__ __forceinline__ void load_wfrags(const u16* __restrict__ wimg, int sub0,
                                            int wid, int lane, short8 bfp[8]) {
#pragma unroll
    for (int kc = 0; kc < 2; ++kc)
#pragma unroll
        for (int ni = 0; ni < 4; ++ni)
            bfp[kc * 4 + ni] = *(const short8*)
                &wimg[(((size_t)(sub0 + kc) * 16 + wid * 4 + ni) * 64 + lane) * 8];
}

// ---------------------------------------------------------------- main fused DCN GEMM
// 1-D grid 512: b = gid%8 (XCD-affine), m-tile = gid/8. 256 thr = 4 waves;
// wave w: 64 pos x n in [w*64, w*64+64). Step = 64 channels (2 MFMA sub-steps).
__launch_bounds__(256, 2)
__global__ void k_dcn(const u16* __restrict__ xt, const u16* __restrict__ wimg,
                      const float* __restrict__ offp, const float* __restrict__ mskp,
                      float* __restrict__ out, float* __restrict__ stats) {
    __shared__ __align__(16) float meta_w[9 * 64 * 4];   // 9216 B
    __shared__ __align__(16) int   meta_i[9 * 64 * 4];   // 9216 B
    __shared__ __align__(16) u16   lds_v[2][64 * VROW];  // 18432 B dbuf val tile

    const int tid = threadIdx.x;
    const int gid = blockIdx.x;
    const int b   = gid & 7;            // XCD-affine: all blocks on XCD j share batch j
    const int m0  = (gid >> 3) * 64;
    const int lane = tid & 63, wid = tid >> 6;
    const int col = lane & 15, quad = lane >> 4;
    const int gpos = tid >> 2, oct = tid & 3;   // gather role: (pos, 16-ch octet)

    const u16* xtb = xt + ((size_t)b << 20);

    // ---- bilinear meta for 64 positions x 9 kernel points, once
    for (int it = tid; it < 576; it += 256) {
        const int pos = it & 63, k = it >> 6;
        const int pg = m0 + pos;
        const int hh = pg >> 6, wwi = pg & 63;
        const float dy = offp[((size_t)(b * 18 + 2 * k) << 12) + pg];
        const float dx = offp[((size_t)(b * 18 + 2 * k + 1) << 12) + pg];
        const float mv = mskp[((size_t)(b * 9 + k) << 12) + pg];
        const float ys = (float)(hh + (k / 3) - 1) + dy;
        const float xs = (float)(wwi + (k % 3) - 1) + dx;
        const float y0f = floorf(ys), x0f = floorf(xs);
        const int y0 = (int)y0f, x0 = (int)x0f;
        const float wy1 = ys - y0f, wx1 = xs - x0f;
        const float wy0 = 1.f - wy1, wx0 = 1.f - wx1;
        const int y1 = y0 + 1, x1 = x0 + 1;
        const float vy0 = (y0 >= 0 && y0 < H_) ? 1.f : 0.f;
        const float vy1 = (y1 >= 0 && y1 < H_) ? 1.f : 0.f;
        const float vx0 = (x0 >= 0 && x0 < W_) ? 1.f : 0.f;
        const float vx1 = (x1 >= 0 && x1 < W_) ? 1.f : 0.f;
        const int y0c = min(max(y0, 0), H_ - 1), y1c = min(max(y1, 0), H_ - 1);
        const int x0c = min(max(x0, 0), W_ - 1), x1c = min(max(x1, 0), W_ - 1);
        meta_w[it * 4 + 0] = mv * wy0 * wx0 * vy0 * vx0;
        meta_w[it * 4 + 1] = mv * wy0 * wx1 * vy0 * vx1;
        meta_w[it * 4 + 2] = mv * wy1 * wx0 * vy1 * vx0;
        meta_w[it * 4 + 3] = mv * wy1 * wx1 * vy1 * vx1;
        meta_i[it * 4 + 0] = y0c * W_ + x0c;
        meta_i[it * 4 + 1] = y0c * W_ + x1c;
        meta_i[it * 4 + 2] = y1c * W_ + x0c;
        meta_i[it * 4 + 3] = y1c * W_ + x1c;
    }
    __syncthreads();

    // ---- prologue: stage step 0
    uint4 g[8]; f32x4 mw; short8 bfp[8];
    issue_gather(xtb, &meta_w[0], &meta_i[0], 0, gpos, oct, g, mw);
    load_wfrags(wimg, 0, wid, lane, bfp);
    interp_store(g, mw, &lds_v[0][gpos * VROW + oct * 16]);
    __syncthreads();

    f32x4 acc[4][4];
#pragma unroll
    for (int i = 0; i < 4; ++i)
#pragma unroll
        for (int j = 0; j < 4; ++j) acc[i][j] = (f32x4){0.f, 0.f, 0.f, 0.f};

#pragma unroll 2
    for (int s = 0; s < NSTEP; ++s) {
        const int p = s & 1;
        short8 bcur[8];
#pragma unroll
        for (int i = 0; i < 8; ++i) bcur[i] = bfp[i];

        // issue next step's loads first (max slack before their use)
        const bool pf = (s + 1 < NSTEP);
        if (pf) {
            const int sn = s + 1;
            const int kn = sn >> 2, c0n = (sn & 3) * 64;
            issue_gather(xtb, &meta_w[kn * 256], &meta_i[kn * 256], c0n, gpos, oct, g, mw);
            load_wfrags(wimg, 2 * sn, wid, lane, bfp);
        }

        // compute current step: 2 sub-steps of 32 ch
#pragma unroll
        for (int kc = 0; kc < 2; ++kc) {
            short8 af[4];
#pragma unroll
            for (int mi = 0; mi < 4; ++mi)
                af[mi] = *(const short8*)
                    &lds_v[p][(mi * 16 + col) * VROW + kc * 32 + quad * 8];
#pragma unroll
            for (int mi = 0; mi < 4; ++mi)
#pragma unroll
                for (int ni = 0; ni < 4; ++ni)
                    acc[mi][ni] = __builtin_amdgcn_mfma_f32_16x16x32_bf16(
                        af[mi], bcur[kc * 4 + ni], acc[mi][ni], 0, 0, 0);
        }

        // interp + stage next buffer
        if (pf) interp_store(g, mw, &lds_v[1 - p][gpos * VROW + oct * 16]);
        __syncthreads();
    }

    // ---- epilogue: store pre-GN output. D: row(pos)=quad*4+r, col(o)=lane&15.
#pragma unroll
    for (int mi = 0; mi < 4; ++mi)
#pragma unroll
        for (int ni = 0; ni < 4; ++ni) {
            const int o  = wid * 64 + ni * 16 + col;
            const int pg = m0 + mi * 16 + quad * 4;
            *(f32x4*)(out + (((size_t)b * O_ + o) << 12) + pg) = acc[mi][ni];
        }

    // ---- GN stats: (wave, ni) = one 16-channel group x 64 positions
#pragma unroll
    for (int ni = 0; ni < 4; ++ni) {
        float s = 0.f, s2 = 0.f;
#pragma unroll
        for (int mi = 0; mi < 4; ++mi) {
            f32x4 v = acc[mi][ni];
            s  += v.x + v.y + v.z + v.w;
            s2 += v.x * v.x + v.y * v.y + v.z * v.z + v.w * v.w;
        }
#pragma unroll
        for (int d = 32; d > 0; d >>= 1) {
            s  += __shfl_xor(s, d, 64);
            s2 += __shfl_xor(s2, d, 64);
        }
        if (lane == 0) {
            const int gI = wid * 4 + ni;
            atomicAdd(&stats[b * GROUPS_ + gI], s);
            atomicAdd(&stats[128 + b * GROUPS_ + gI], s2);
        }
    }
}

// ---------------------------------------------------------------- apply GN in place (fin folded in)
__global__ void k_gn(float* __restrict__ out, const float* __restrict__ stats,
                     const float* __restrict__ gamma, const float* __restrict__ beta) {
    const int blk = blockIdx.x;            // b*256 + o
    const int b = blk >> 8, o = blk & 255;
    const int gI = b * GROUPS_ + (o >> 4);
    const float n = 65536.f;               // (C/G)*H*W
    const float mean = stats[gI] / n;
    const float var  = stats[128 + gI] / n - mean * mean;
    const float inv  = rsqrtf(fmaxf(var, 0.f) + EPS_);
    const float scale = inv * gamma[o];
    const float shift = beta[o] - mean * scale;
    f32x4* p = (f32x4*)(out + ((size_t)blk << 12));
    const int t = threadIdx.x;
#pragma unroll
    for (int i = 0; i < 4; ++i) {
        f32x4 v = p[t + i * 256];
        p[t + i * 256] = v * scale + shift;
    }
}

extern "C" void kernel_launch(void* const* d_in, const int* in_sizes, int n_in,
                              void* d_out, int out_size, void* d_ws, size_t ws_size,
                              hipStream_t stream) {
    const float* x     = (const float*)d_in[0];
    const float* offp  = (const float*)d_in[1];
    const float* mskp  = (const float*)d_in[2];
    const float* w     = (const float*)d_in[3];
    const float* gamma = (const float*)d_in[4];
    const float* beta  = (const float*)d_in[5];
    float* outp = (float*)d_out;

    u16*   xt    = (u16*)d_ws;
    u16*   wimg  = (u16*)((char*)d_ws + WIMG_OFF);
    float* stats = (float*)((char*)d_ws + STATS_OFF);

    hipMemsetAsync(stats, 0, 1024, stream);
    k_prep<<<dim3(8192 + 72), dim3(256), 0, stream>>>(x, xt, w, wimg);
    k_dcn<<<dim3(512), dim3(256), 0, stream>>>(xt, wimg, offp, mskp, outp, stats);
    k_gn<<<dim3(2048), dim3(256), 0, stream>>>(outp, stats, gamma, beta);
}